// Round 1
// baseline (237.695 us; speedup 1.0000x reference)
//
#include <hip/hip_runtime.h>

// TranslationLayer: out[b,i,j] = in[b, i+dy[b], j-dx[b]] if in-bounds else 0
// B,H,W,C = 128,512,512,1 fp32. Pure memory-bound shift-gather.
//
// R4: ILP widening. Previous version: 1 float4 per thread -> one load in
// flight, then a serial load->vmcnt(0)->4x ds_bpermute->store chain. Kernel
// ran ~70us (~3.8 TB/s) vs ~43us copy roofline. Now each thread handles 4
// float4 groups (block = 1024 groups = 8 rows of ONE sample): 4 independent
// dwordx4 loads issue back-to-back, shuffle latency of chunk k hides under
// loads of later chunks. dx/dy/q/r are now block-uniform (derived from
// blockIdx only) -> s_load + SALU instead of per-lane VALU.
// Aligned-group + wave-uniform funnel-shift scheme unchanged (verified,
// absmax 0.0).

#define TB 128
#define TH 512
#define TW 512
#define W4 (TW / 4)   // 128 float4 groups per row
#define KPT 4         // float4 groups per thread

typedef float f4 __attribute__((ext_vector_type(4)));

__global__ __launch_bounds__(256) void TranslationLayer_63350767616318_kernel(
    const float* __restrict__ in,
    const int*   __restrict__ dx,
    const int*   __restrict__ dy,
    float*       __restrict__ out)
{
    const int t    = threadIdx.x;
    const int base = blockIdx.x << 10;          // 1024 groups per block = 8 rows
    const int b    = base >> 16;                // 65536 groups per sample
    const int i0   = (base >> 7) & (TH - 1);    // first row of this block

    const int dxb  = dx[b];                     // block-uniform -> s_load
    const int dyb  = dy[b];

    const int j4   = t & (W4 - 1);              // same for every k (256 % 128 == 0)
    const int half = t >> 7;                    // which of the 2 rows per chunk
    const int tsh  = -dxb;
    const int q    = tsh >> 2;                  // block-uniform group offset
    const int r    = tsh & 3;                   // block-uniform residue
    const int a    = j4 + q;                    // source group for this lane
    const bool ain = (unsigned)a < (unsigned)W4;
    const int lane = t & 63;
    const f4* __restrict__ in4 = (const f4*)in;

    int  si[KPT];
    bool rv[KPT];
    f4   v[KPT];
#pragma unroll
    for (int k = 0; k < KPT; ++k) {             // straight-line: 4 loads batch
        si[k] = i0 + 2 * k + half + dyb;
        rv[k] = (unsigned)si[k] < (unsigned)TH; // row in range (wave-uniform)
        v[k]  = (f4)(0.f);
        if (rv[k] & ain)
            v[k] = in4[(b * TH + si[k]) * W4 + a];
    }

    f4 res[KPT];
    if (r == 0) {                               // shift multiple of 4 floats
#pragma unroll
        for (int k = 0; k < KPT; ++k) res[k] = v[k];
    } else {
#pragma unroll
        for (int k = 0; k < KPT; ++k) {
            // neighbor group A[a+1] == lane(i+1)'s v[k] (already zero-masked)
            f4 v1;
            v1.x = __shfl_down(v[k].x, 1);
            v1.y = __shfl_down(v[k].y, 1);
            v1.z = __shfl_down(v[k].z, 1);
            v1.w = __shfl_down(v[k].w, 1);
            if (lane == 63) {                   // last lane: no neighbor in wave
                v1 = (f4)(0.f);
                if (rv[k] && (unsigned)(a + 1) < (unsigned)W4)
                    v1 = in4[(b * TH + si[k]) * W4 + (a + 1)];
            }
            f4 o;
            if (r == 1)      { o.x = v[k].y; o.y = v[k].z; o.z = v[k].w; o.w = v1.x; }
            else if (r == 2) { o.x = v[k].z; o.y = v[k].w; o.z = v1.x;   o.w = v1.y; }
            else             { o.x = v[k].w; o.y = v1.x;   o.z = v1.y;   o.w = v1.z; }
            res[k] = o;
        }
    }

#pragma unroll
    for (int k = 0; k < KPT; ++k)               // output never re-read: NT store
        __builtin_nontemporal_store(res[k], (f4*)out + (base + k * 256 + t));
}

extern "C" void kernel_launch(void* const* d_in, const int* in_sizes, int n_in,
                              void* d_out, int out_size, void* d_ws, size_t ws_size,
                              hipStream_t stream)
{
    const float* in  = (const float*)d_in[0];
    const int*   dx  = (const int*)d_in[1];
    const int*   dy  = (const int*)d_in[2];
    float*       out = (float*)d_out;

    // total float4s = 128*512*128 = 8,388,608 ; /(256 threads * 4 per thread)
    const int total4 = TB * TH * W4;
    dim3 grid(total4 / (256 * KPT)), block(256);   // 8192 blocks
    TranslationLayer_63350767616318_kernel<<<grid, block, 0, stream>>>(in, dx, dy, out);
}

// Round 3
// 226.587 us; speedup vs baseline: 1.0490x; 1.0490x over previous
//
#include <hip/hip_runtime.h>

// TranslationLayer: out[b,i,j] = in[b, i+dy[b], j-dx[b]] if in-bounds else 0
// B,H,W,C = 128,512,512,1 fp32. Pure memory-bound shift-gather.
//
// R5 (resubmit after infra failure — container acquisition failed, kernel
// never ran): kill the DS path. R4's ILP widening was neutral->negative,
// falsifying the latency theory: the shuffle funnel was a THROUGHPUT tax
// (4 ds_bpermute + lgkm wait + divergent lane-63 fixup with exec juggling
// per group), not a latency problem. Replace the cross-lane funnel with a
// second ALIGNED vmem load of the neighbor group row4[a+1]: lane i's v1 ==
// lane i+1's v0, so the second load hits the same cache lines (L1/L2 serve
// it -> no extra HBM traffic). No DS ops, no lgkmcnt, no divergence, no
// wave-edge case; combine is pure register selects under a block-uniform r
// branch. KPT back to 1 (R4 showed per-thread ILP buys nothing at this TLP).
// Aligned 4-float groups are fully in- or out-of-range -> group-level
// zero-fill (verified absmax 0.0). NT store kept (output never re-read).

#define TB 128
#define TH 512
#define TW 512
#define W4 (TW / 4)   // 128 float4 groups per row

typedef float f4 __attribute__((ext_vector_type(4)));

__global__ __launch_bounds__(256) void TranslationLayer_63350767616318_kernel(
    const float* __restrict__ in,
    const int*   __restrict__ dx,
    const int*   __restrict__ dy,
    float*       __restrict__ out)
{
    const int tid = threadIdx.x;
    const int b   = blockIdx.x >> 8;                       // 256 blocks/sample
    const int i   = ((blockIdx.x << 1) | (tid >> 7)) & (TH - 1);
    const int j4  = tid & (W4 - 1);

    const int dxb = dx[b];                                  // block-uniform
    const int si  = i + dy[b];                              // wave-uniform row

    f4 res = (f4)(0.f);
    if ((unsigned)si < (unsigned)TH) {                      // wave-uniform
        const f4* __restrict__ row4 =
            (const f4*)in + (size_t)(b * TH + si) * W4;
        const int t = -dxb;
        const int q = t >> 2;     // block-uniform group offset
        const int r = t & 3;      // block-uniform residue
        const int a = j4 + q;     // source group for this lane

        f4 v0 = (f4)(0.f);
        if ((unsigned)a < (unsigned)W4) v0 = row4[a];

        if (r == 0) {
            res = v0;             // shift is a multiple of 4 floats
        } else {
            // neighbor group: second aligned load, L1/L2-resident
            // (same lines as lane i+1's v0) -> no HBM over-fetch
            f4 v1 = (f4)(0.f);
            if ((unsigned)(a + 1) < (unsigned)W4) v1 = row4[a + 1];
            f4 o;
            if (r == 1)      { o.x = v0.y; o.y = v0.z; o.z = v0.w; o.w = v1.x; }
            else if (r == 2) { o.x = v0.z; o.y = v0.w; o.z = v1.x; o.w = v1.y; }
            else             { o.x = v0.w; o.y = v1.x; o.z = v1.y; o.w = v1.z; }
            res = o;
        }
    }
    const int idx = blockIdx.x * 256 + tid;                 // output float4 id
    __builtin_nontemporal_store(res, (f4*)out + idx);
}

extern "C" void kernel_launch(void* const* d_in, const int* in_sizes, int n_in,
                              void* d_out, int out_size, void* d_ws, size_t ws_size,
                              hipStream_t stream)
{
    const float* in  = (const float*)d_in[0];
    const int*   dx  = (const int*)d_in[1];
    const int*   dy  = (const int*)d_in[2];
    float*       out = (float*)d_out;

    // total float4s = 128*512*128 = 8,388,608 ; /256 threads = 32768 blocks
    const int total4 = TB * TH * W4;
    dim3 grid(total4 / 256), block(256);
    TranslationLayer_63350767616318_kernel<<<grid, block, 0, stream>>>(in, dx, dy, out);
}

// Round 4
// 223.521 us; speedup vs baseline: 1.0634x; 1.0137x over previous
//
#include <hip/hip_runtime.h>

// TranslationLayer: out[b,i,j] = in[b, i+dy[b], j-dx[b]] if in-bounds else 0
// B,H,W,C = 128,512,512,1 fp32. Pure memory-bound shift-gather.
//
// R6: make it a memcpy. R5 (drop DS funnel for a second aligned load) gained
// only ~4us (kernel ~70 -> ~66us vs ~43us copy floor), so the select tree
// wasn't the main tax; the remaining suspect is the SECOND load stream
// (v1 = row4[a+1]) whose lines are in-flight v0 misses — if L1 MSHRs don't
// merge, each v1 is an L2 round trip occupying the memory pipe.
// New scheme: ONE unaligned (4B-aligned) dwordx4 load per lane, straight
// from row + 4*j4 + t. Source addresses are always float-aligned; gfx950's
// unaligned-access-mode makes 4B-aligned dwordx4 legal (alignment declared
// via aligned(4) ext-vector). Wave still reads one contiguous span ->
// coalesced; edge lines are shared with neighboring rows -> no HBM
// over-fetch. Zero-fill edges handled per-element only in the rare partial
// lanes (~20 of 128 per row). Fast path: 1 load + 1 NT store + ~12 VALU.

#define TB 128
#define TH 512
#define TW 512
#define W4 (TW / 4)   // 128 float4 groups per row

typedef float f4  __attribute__((ext_vector_type(4)));
typedef float f4u __attribute__((ext_vector_type(4), aligned(4)));  // 4B-aligned view

__global__ __launch_bounds__(256) void TranslationLayer_63350767616318_kernel(
    const float* __restrict__ in,
    const int*   __restrict__ dx,
    const int*   __restrict__ dy,
    float*       __restrict__ out)
{
    const int tid = threadIdx.x;
    const int b   = blockIdx.x >> 8;                       // 256 blocks/sample
    const int i   = ((blockIdx.x << 1) | (tid >> 7)) & (TH - 1);
    const int j4  = tid & (W4 - 1);

    const int t   = -dx[b];                                 // block-uniform
    const int si  = i + dy[b];                              // wave-uniform row

    f4 res = (f4)(0.f);
    if ((unsigned)si < (unsigned)TH) {                      // wave-uniform
        const float* __restrict__ row = in + (size_t)(b * TH + si) * TW;
        const int s0 = (j4 << 2) + t;                       // source float idx

        if (s0 >= 0 && s0 <= TW - 4) {
            // fast path: whole 4-float chunk in range -> one unaligned load
            res = *(const f4u*)(row + s0);
        } else if (s0 > -4 && s0 < TW) {
            // partial chunk at the row edge (rare: <=2 lanes per half-row)
#pragma unroll
            for (int e = 0; e < 4; ++e) {
                const int s = s0 + e;
                float x = 0.f;
                if ((unsigned)s < (unsigned)TW) x = row[s];
                res[e] = x;
            }
        }
        // else fully out of range: zeros
    }
    const int idx = blockIdx.x * 256 + tid;                 // output float4 id
    __builtin_nontemporal_store(res, (f4*)out + idx);
}

extern "C" void kernel_launch(void* const* d_in, const int* in_sizes, int n_in,
                              void* d_out, int out_size, void* d_ws, size_t ws_size,
                              hipStream_t stream)
{
    const float* in  = (const float*)d_in[0];
    const int*   dx  = (const int*)d_in[1];
    const int*   dy  = (const int*)d_in[2];
    float*       out = (float*)d_out;

    // total float4s = 128*512*128 = 8,388,608 ; /256 threads = 32768 blocks
    const int total4 = TB * TH * W4;
    dim3 grid(total4 / 256), block(256);
    TranslationLayer_63350767616318_kernel<<<grid, block, 0, stream>>>(in, dx, dy, out);
}

// Round 5
// 223.345 us; speedup vs baseline: 1.0642x; 1.0008x over previous
//
#include <hip/hip_runtime.h>

// TranslationLayer: out[b,i,j] = in[b, i+dy[b], j-dx[b]] if in-bounds else 0
// B,H,W,C = 128,512,512,1 fp32. Pure memory-bound shift-gather.
//
// R7: NT-store A/B. R6 (single unaligned load, memcpy-shaped stream) gained
// only ~2us — kernel ~64us vs the 43us measured copy floor (m13: 6.29 TB/s
// float4 copy). Instruction-stream theories are now exonerated (R5: DS
// funnel, R6: dual load stream, R4: per-wave overhead). The one constant
// never A/B'd across all rounds is __builtin_nontemporal_store: the `nt`
// cache policy (evict-first, reduced L2 write combining) differs from the
// normal stores the 6.7 TB/s fills use. This round flips EXACTLY that one
// variable: NT store -> plain store. Everything else byte-identical to R6.
// If neutral: store policy exonerated -> next: source-aligned loads + DPP
// row-shift funnel (kill the misaligned-read 2x TA request split).

#define TB 128
#define TH 512
#define TW 512
#define W4 (TW / 4)   // 128 float4 groups per row

typedef float f4  __attribute__((ext_vector_type(4)));
typedef float f4u __attribute__((ext_vector_type(4), aligned(4)));  // 4B-aligned view

__global__ __launch_bounds__(256) void TranslationLayer_63350767616318_kernel(
    const float* __restrict__ in,
    const int*   __restrict__ dx,
    const int*   __restrict__ dy,
    float*       __restrict__ out)
{
    const int tid = threadIdx.x;
    const int b   = blockIdx.x >> 8;                       // 256 blocks/sample
    const int i   = ((blockIdx.x << 1) | (tid >> 7)) & (TH - 1);
    const int j4  = tid & (W4 - 1);

    const int t   = -dx[b];                                 // block-uniform
    const int si  = i + dy[b];                              // wave-uniform row

    f4 res = (f4)(0.f);
    if ((unsigned)si < (unsigned)TH) {                      // wave-uniform
        const float* __restrict__ row = in + (size_t)(b * TH + si) * TW;
        const int s0 = (j4 << 2) + t;                       // source float idx

        if (s0 >= 0 && s0 <= TW - 4) {
            // fast path: whole 4-float chunk in range -> one unaligned load
            res = *(const f4u*)(row + s0);
        } else if (s0 > -4 && s0 < TW) {
            // partial chunk at the row edge (rare: <=2 lanes per half-row)
#pragma unroll
            for (int e = 0; e < 4; ++e) {
                const int s = s0 + e;
                float x = 0.f;
                if ((unsigned)s < (unsigned)TW) x = row[s];
                res[e] = x;
            }
        }
        // else fully out of range: zeros
    }
    const int idx = blockIdx.x * 256 + tid;                 // output float4 id
    ((f4*)out)[idx] = res;                                  // R7: plain store (was NT)
}

extern "C" void kernel_launch(void* const* d_in, const int* in_sizes, int n_in,
                              void* d_out, int out_size, void* d_ws, size_t ws_size,
                              hipStream_t stream)
{
    const float* in  = (const float*)d_in[0];
    const int*   dx  = (const int*)d_in[1];
    const int*   dy  = (const int*)d_in[2];
    float*       out = (float*)d_out;

    // total float4s = 128*512*128 = 8,388,608 ; /256 threads = 32768 blocks
    const int total4 = TB * TH * W4;
    dim3 grid(total4 / 256), block(256);
    TranslationLayer_63350767616318_kernel<<<grid, block, 0, stream>>>(in, dx, dy, out);
}